// Round 1
// baseline (95.056 us; speedup 1.0000x reference)
//
#include <hip/hip_runtime.h>

// BuzzLoss: per-row exclusive cumprod of (1-conf), weighted sums, negated mean.
// One wave (64 lanes) per row of T=1024; lane i owns 16 contiguous elements.

#define TLEN 1024
#define CHUNK 16          // TLEN / 64
#define WAVES_PER_BLOCK 16

__global__ __launch_bounds__(1024)
void buzz_loss_kernel(const float* __restrict__ conf,
                      const float* __restrict__ acc,
                      float* __restrict__ out,
                      float neg_inv_b) {
    const int lane = threadIdx.x & 63;
    const int wave = threadIdx.x >> 6;                 // 0..15
    const long long row = (long long)blockIdx.x * WAVES_PER_BLOCK + wave;

    const float* cp = conf + row * TLEN + lane * CHUNK;
    const float* ap = acc  + row * TLEN + lane * CHUNK;

    float4 cv[4], av[4];
    #pragma unroll
    for (int j = 0; j < 4; ++j) {
        cv[j] = ((const float4*)cp)[j];
        av[j] = ((const float4*)ap)[j];
    }
    float c[CHUNK], a[CHUNK];
    #pragma unroll
    for (int j = 0; j < 4; ++j) {
        c[4*j+0] = cv[j].x; c[4*j+1] = cv[j].y; c[4*j+2] = cv[j].z; c[4*j+3] = cv[j].w;
        a[4*j+0] = av[j].x; a[4*j+1] = av[j].y; a[4*j+2] = av[j].z; a[4*j+3] = av[j].w;
    }

    // local product of (1-c) over this lane's 16 elements
    float p = 1.0f;
    #pragma unroll
    for (int k = 0; k < CHUNK; ++k) p *= (1.0f - c[k]);

    // inclusive multiplicative scan across 64 lanes, then shift to exclusive
    float incl = p;
    #pragma unroll
    for (int off = 1; off < 64; off <<= 1) {
        float v = __shfl_up(incl, off, 64);
        if (lane >= off) incl *= v;
    }
    float prefix = __shfl_up(incl, 1, 64);
    if (lane == 0) prefix = 1.0f;

    // sequential pass over the lane's chunk with running exclusive product
    float run = prefix;
    float sba = 0.0f, sb = 0.0f;
    #pragma unroll
    for (int k = 0; k < CHUNK; ++k) {
        float b = c[k] * run;
        sba += b * a[k];
        sb  += b;
        run *= (1.0f - c[k]);
    }

    // acc[row, T-1] lives in lane 63's a[15]
    float alast = __shfl(a[CHUNK - 1], 63, 64);

    // wave reduction (butterfly)
    #pragma unroll
    for (int off = 32; off; off >>= 1) {
        sba += __shfl_xor(sba, off, 64);
        sb  += __shfl_xor(sb,  off, 64);
    }

    float score = sba + (1.0f - sb) * alast;

    __shared__ float smem[WAVES_PER_BLOCK];
    if (lane == 0) smem[wave] = score;
    __syncthreads();
    if (threadIdx.x == 0) {
        float s = 0.0f;
        #pragma unroll
        for (int w = 0; w < WAVES_PER_BLOCK; ++w) s += smem[w];
        atomicAdd(out, s * neg_inv_b);
    }
}

extern "C" void kernel_launch(void* const* d_in, const int* in_sizes, int n_in,
                              void* d_out, int out_size, void* d_ws, size_t ws_size,
                              hipStream_t stream) {
    const float* conf = (const float*)d_in[0];
    const float* acc  = (const float*)d_in[1];
    float* out = (float*)d_out;

    const int total = in_sizes[0];
    const int B = total / TLEN;                        // 8192
    const int blocks = B / WAVES_PER_BLOCK;            // 512

    // d_out is poisoned 0xAA before each replay — zero it for the atomics.
    hipMemsetAsync(d_out, 0, sizeof(float), stream);

    buzz_loss_kernel<<<blocks, 64 * WAVES_PER_BLOCK, 0, stream>>>(
        conf, acc, out, -1.0f / (float)B);
}

// Round 2
// 91.114 us; speedup vs baseline: 1.0433x; 1.0433x over previous
//
#include <hip/hip_runtime.h>

// BuzzLoss: per-row exclusive cumprod of (1-conf), weighted sums, negated mean.
// One wave (64 lanes) per row of T=1024, coalesced segment-major layout:
// row = 4 segments x 256 elems; lane i owns the 4 contiguous elems at 4*i
// within each segment, so every dwordx4 load is one contiguous 1 KB wave txn.

#define TLEN 1024
#define NSEG 4            // segments per row
#define SEGW 256          // elements per segment (64 lanes * 4)
#define WAVES_PER_BLOCK 16

__global__ __launch_bounds__(1024)
void buzz_loss_partial(const float* __restrict__ conf,
                       const float* __restrict__ acc,
                       float* __restrict__ partial) {
    const int lane = threadIdx.x & 63;
    const int wave = threadIdx.x >> 6;                 // 0..15
    const long long row = (long long)blockIdx.x * WAVES_PER_BLOCK + wave;

    const float* crow = conf + row * TLEN;
    const float* arow = acc  + row * TLEN;

    // load all 4 segments up front (8 coalesced 1KB wave loads, max MLP)
    float4 cv[NSEG], av[NSEG];
    #pragma unroll
    for (int s = 0; s < NSEG; ++s) {
        cv[s] = ((const float4*)(crow + s * SEGW))[lane];
        av[s] = ((const float4*)(arow + s * SEGW))[lane];
    }

    float carry = 1.0f;    // product of (1-c) over all preceding segments
    float sba = 0.0f, sb = 0.0f;
    float alast = 0.0f;

    #pragma unroll
    for (int s = 0; s < NSEG; ++s) {
        float c[4] = {cv[s].x, cv[s].y, cv[s].z, cv[s].w};
        float a[4] = {av[s].x, av[s].y, av[s].z, av[s].w};

        // local product of (1-c) over this lane's 4 elements
        float p = (1.0f - c[0]) * (1.0f - c[1]) * (1.0f - c[2]) * (1.0f - c[3]);

        // inclusive multiplicative scan across 64 lanes
        float incl = p;
        #pragma unroll
        for (int off = 1; off < 64; off <<= 1) {
            float v = __shfl_up(incl, off, 64);
            if (lane >= off) incl *= v;
        }
        // exclusive prefix for this lane, scaled by segment carry
        float prefix = __shfl_up(incl, 1, 64);
        if (lane == 0) prefix = 1.0f;
        float run = carry * prefix;

        #pragma unroll
        for (int k = 0; k < 4; ++k) {
            float b = c[k] * run;
            sba += b * a[k];
            sb  += b;
            run *= (1.0f - c[k]);
        }

        // total segment product lives in lane 63's incl
        carry *= __shfl(incl, 63, 64);

        if (s == NSEG - 1) alast = __shfl(a[3], 63, 64);  // acc[row, T-1]
    }

    // wave butterfly reduction
    #pragma unroll
    for (int off = 32; off; off >>= 1) {
        sba += __shfl_xor(sba, off, 64);
        sb  += __shfl_xor(sb,  off, 64);
    }
    float score = sba + (1.0f - sb) * alast;

    __shared__ float smem[WAVES_PER_BLOCK];
    if (lane == 0) smem[wave] = score;
    __syncthreads();
    if (threadIdx.x == 0) {
        float s = 0.0f;
        #pragma unroll
        for (int w = 0; w < WAVES_PER_BLOCK; ++w) s += smem[w];
        partial[blockIdx.x] = s;
    }
}

// Single-block final reduction: writes d_out directly (no zero-init needed).
__global__ __launch_bounds__(512)
void buzz_loss_reduce(const float* __restrict__ partial, float* __restrict__ out,
                      float neg_inv_b, int n) {
    const int tid = threadIdx.x;                       // 512 threads
    float v = (tid < n) ? partial[tid] : 0.0f;
    #pragma unroll
    for (int off = 32; off; off >>= 1) v += __shfl_xor(v, off, 64);
    __shared__ float smem[8];
    if ((tid & 63) == 0) smem[tid >> 6] = v;
    __syncthreads();
    if (tid == 0) {
        float s = 0.0f;
        #pragma unroll
        for (int w = 0; w < 8; ++w) s += smem[w];
        out[0] = s * neg_inv_b;
    }
}

extern "C" void kernel_launch(void* const* d_in, const int* in_sizes, int n_in,
                              void* d_out, int out_size, void* d_ws, size_t ws_size,
                              hipStream_t stream) {
    const float* conf = (const float*)d_in[0];
    const float* acc  = (const float*)d_in[1];
    float* out = (float*)d_out;
    float* partial = (float*)d_ws;                     // 512 floats of scratch

    const int total = in_sizes[0];
    const int B = total / TLEN;                        // 8192
    const int blocks = B / WAVES_PER_BLOCK;            // 512

    buzz_loss_partial<<<blocks, 64 * WAVES_PER_BLOCK, 0, stream>>>(conf, acc, partial);
    buzz_loss_reduce<<<1, 512, 0, stream>>>(partial, out, -1.0f / (float)B, blocks);
}